// Round 1
// baseline (259.510 us; speedup 1.0000x reference)
//
#include <hip/hip_runtime.h>

// ---------------------------------------------------------------------------
// SelfCrossAttention: B=4, T=1024+1024, d=512, H=8, hd=64. fp32 I/O,
// bf16 MFMA internals.
// prep (X->bf16; W_self/W_cross -> wt[n][k], q section pre-scaled by
//       0.125*log2(e) so attention runs in exp2 domain; W_proj -> wtp[n][k])
//   -> qkv (128x128 LDS GEMM staged via global_load_lds width=16, unpadded
//           stride-32 LDS; V stored transposed+window-permuted for K=32 PV)
//   -> attn (S^T flash, 32q/wave, 4-way key split; exp2 softmax, l summed by
//            ones-A MFMA from the SAME packed P regs; A/B software pipeline
//            prefetching next window's K+times; launch_bounds(256,3) caps
//            VGPR+AGPR to 170 -> 3 waves/SIMD vs previous ~240 -> 2)
//   -> proj (same glds GEMM, bf16 wtp, fp32 out, tuple split).
// ---------------------------------------------------------------------------

typedef short     bf16x8 __attribute__((ext_vector_type(8)));
typedef short     bf16x4 __attribute__((ext_vector_type(4)));
typedef float     f32x4  __attribute__((ext_vector_type(4)));
typedef int       i32x4  __attribute__((ext_vector_type(4)));

#define DI __device__ __forceinline__

DI unsigned short f2b(float f) {            // fp32 -> bf16 bits, RNE-ish
    union { float f; unsigned int u; } x; x.f = f;
    unsigned int r = x.u + 0x7fffu + ((x.u >> 16) & 1u);
    return (unsigned short)(r >> 16);
}
DI unsigned int fbits(float f) { union { float f; unsigned int u; } x; x.f = f; return x.u; }
DI float bitsf(unsigned int u) { union { unsigned int u; float f; } x; x.u = u; return x.f; }
DI float b2f(unsigned short v) { return bitsf(((unsigned int)v) << 16); }

DI void glds16(const unsigned short* g, unsigned short* l) {   // 16B global->LDS
    __builtin_amdgcn_global_load_lds(
        (const __attribute__((address_space(1))) void*)g,
        (__attribute__((address_space(3))) void*)l, 16, 0, 0);
}

#define QSCALE 0.18033688011112042f   // 0.125 * log2(e): exp2-domain scores

// ---------------------------------------------------------------------------
// prep: [0,2048): X fp32 -> bf16 flat.
//       [2048,2432): W_self/W_cross -> wt[src][n][k], q-section * QSCALE
//       [2432,2496): W_proj -> wtp[n][k]
// ---------------------------------------------------------------------------
__global__ __launch_bounds__(256)
void prep_kernel(const float* __restrict__ Xs, const float* __restrict__ Xc,
                 const float* __restrict__ Ws, const float* __restrict__ Wc,
                 const float* __restrict__ Wp,
                 unsigned short* __restrict__ xb, unsigned short* __restrict__ wt,
                 unsigned short* __restrict__ wtp)
{
    const int bid = blockIdx.x, tid = threadIdx.x;
    if (bid < 2048) {
        int idx = bid * 2048 + tid * 8;
        const float* s = (idx < 2097152) ? (Xs + idx) : (Xc + idx - 2097152);
        f32x4 a0 = *(const f32x4*)s;
        f32x4 a1 = *(const f32x4*)(s + 4);
        bf16x8 v;
#pragma unroll
        for (int j = 0; j < 4; ++j) {
            ((unsigned short*)&v)[j]     = f2b(a0[j]);
            ((unsigned short*)&v)[4 + j] = f2b(a1[j]);
        }
        *(bf16x8*)(xb + idx) = v;
        return;
    }
    __shared__ unsigned short Tt[64 * 72];
    const float* W;
    unsigned short* dst;
    int k0, n0, ldn;
    float sc = 1.0f;
    if (bid < 2432) {
        int tj  = bid - 2048;
        int src = tj >= 192;  tj -= src * 192;
        k0  = (tj / 24) * 64;
        n0  = (tj % 24) * 64;
        W   = src ? Wc : Ws;
        ldn = 1536;
        dst = wt + (size_t)src * 786432;
        if (n0 < 512) sc = QSCALE;
    } else {
        int tj = bid - 2432;
        k0  = (tj >> 3) * 64;
        n0  = (tj & 7) * 64;
        W   = Wp;
        ldn = 512;
        dst = wtp;
    }
#pragma unroll
    for (int r = 0; r < 4; ++r) {
        int g  = tid + r * 256;
        int kr = g >> 4, nc4 = (g & 15) * 4;
        f32x4 v = *(const f32x4*)(W + (size_t)(k0 + kr) * ldn + n0 + nc4);
#pragma unroll
        for (int u = 0; u < 4; ++u)
            Tt[(nc4 + u) * 72 + kr] = f2b(v[u] * sc);
    }
    __syncthreads();
#pragma unroll
    for (int r = 0; r < 2; ++r) {
        int c = tid + r * 256;
        int nl = c >> 3, k8 = (c & 7) * 8;
        *(bf16x8*)(dst + (size_t)(n0 + nl) * 512 + k0 + k8) =
            *(const bf16x8*)(Tt + nl * 72 + k8);
    }
}

// ---------------------------------------------------------------------------
// QKV: xb @ wt^T + bias. 128x128 tile, 256 thr, glds-staged unpadded LDS.
// q/k -> [bh][t][j]; v -> vt[bh][j][t'] with the 32-window key permutation.
// ---------------------------------------------------------------------------
__global__ __launch_bounds__(256)
void qkv_kernel(const unsigned short* __restrict__ xb,
                const unsigned short* __restrict__ wt,
                const float* __restrict__ bs, const float* __restrict__ bc,
                unsigned short* __restrict__ qb, unsigned short* __restrict__ kb,
                unsigned short* __restrict__ vtb)
{
    const int src = blockIdx.z;
    const int m0 = blockIdx.x * 128, n0 = blockIdx.y * 128;
    const float* bias = src ? bc : bs;
    const unsigned short* X = xb + (size_t)src * 2097152;
    const unsigned short* W = wt + (size_t)src * 786432;

    __shared__ unsigned short As[128 * 32];
    __shared__ unsigned short Bs[128 * 32];

    const int tid = threadIdx.x, lane = tid & 63, w = tid >> 6;
    const int quad = lane >> 4, r16 = lane & 15;
    const int mrow = (w >> 1) * 64, ncol = (w & 1) * 64;

    const f32x4 fz = {0.f, 0.f, 0.f, 0.f};
    f32x4 acc[4][4];
#pragma unroll
    for (int a = 0; a < 4; ++a)
#pragma unroll
        for (int b = 0; b < 4; ++b) acc[a][b] = fz;

    // glds staging: chunk ci covers rows [ci*16, ci*16+16); lane -> row/koff
    const int ci   = w << 1;
    const int rofs = lane >> 2, kofs = (lane & 3) * 8;
    const unsigned short* gA = X + (size_t)(m0 + ci * 16 + rofs) * 512 + kofs;
    const unsigned short* gB = W + (size_t)(n0 + ci * 16 + rofs) * 512 + kofs;
    unsigned short* lA = As + ci * 512 + lane * 8;
    unsigned short* lB = Bs + ci * 512 + lane * 8;

    for (int k0 = 0; k0 < 512; k0 += 32) {
        glds16(gA + k0, lA);
        glds16(gA + 16 * 512 + k0, lA + 512);
        glds16(gB + k0, lB);
        glds16(gB + 16 * 512 + k0, lB + 512);
        __syncthreads();

        bf16x8 af[4], bfr[4];
#pragma unroll
        for (int ms = 0; ms < 4; ++ms)
            af[ms] = *(const bf16x8*)(As + (mrow + ms * 16 + r16) * 32 + quad * 8);
#pragma unroll
        for (int ns = 0; ns < 4; ++ns)
            bfr[ns] = *(const bf16x8*)(Bs + (ncol + ns * 16 + r16) * 32 + quad * 8);
#pragma unroll
        for (int ms = 0; ms < 4; ++ms)
#pragma unroll
            for (int ns = 0; ns < 4; ++ns)
                acc[ms][ns] = __builtin_amdgcn_mfma_f32_16x16x32_bf16(
                    af[ms], bfr[ns], acc[ms][ns], 0, 0, 0);
        __syncthreads();
    }

#pragma unroll
    for (int ms = 0; ms < 4; ++ms)
#pragma unroll
        for (int ns = 0; ns < 4; ++ns) {
            int n = n0 + ncol + ns * 16 + r16;
            int sec = n >> 9, col = n & 511;
            int hh = col >> 6, j = col & 63;
            float bb = bias[n] * ((sec == 0) ? QSCALE : 1.0f);
            int mb = m0 + mrow + ms * 16 + quad * 4;
            int bi = mb >> 10, tg0 = (mb & 1023) + (src << 10);
            if (sec == 2) {                 // V: transposed + window-permuted
                bf16x4 pk;
#pragma unroll
                for (int i = 0; i < 4; ++i)
                    pk[i] = (short)f2b(acc[ms][ns][i] + bb);
                int r = tg0 & 31;           // 4-aligned
                int pos = (r < 16) ? (r << 1) : (((r - 16) << 1) + 4);
                int tgp = (tg0 & ~31) + pos;
                *(bf16x4*)(vtb + (((size_t)(bi * 8 + hh) * 64 + j) << 11) + tgp) = pk;
            } else {
                unsigned short* dst = (sec == 0) ? qb : kb;
#pragma unroll
                for (int i = 0; i < 4; ++i)
                    dst[(((size_t)(bi * 8 + hh) * 2048 + tg0 + i) << 6) + j] =
                        f2b(acc[ms][ns][i] + bb);
            }
        }
}

// ---------------------------------------------------------------------------
// attn: S^T flash, exp2 domain. Block 256 thr = 4 waves; block = 32 queries
// of one bh; wave = all 32 q x 512 contiguous keys (4-way key split), walked
// as 16 x 32-key windows with an A/B register pipeline: next window's K-tile
// and key-times load while the current window computes. V loads issued at
// window top (covered by QK+softmax). l summed by ones-A MFMA from the same
// packed P. setprio(1) wraps MFMA clusters. Grid 2048: XCD sees 4 bh.
// ---------------------------------------------------------------------------

#define LOADW(P, WI) do {                                                      \
    const unsigned short* kr_ = Kb + (size_t)(((WI) << 5) + r16) * 64 + (quad << 3); \
    P##00 = *(const bf16x8*)(kr_);                                             \
    P##01 = *(const bf16x8*)(kr_ + 32);                                        \
    P##10 = *(const bf16x8*)(kr_ + 1024);                                      \
    P##11 = *(const bf16x8*)(kr_ + 1056);                                      \
    P##t0 = *(const i32x4*)(tw + ((WI) << 5) + (quad << 2));                   \
    P##t1 = *(const i32x4*)(tw + ((WI) << 5) + 16 + (quad << 2));              \
} while (0)

#define DOG(P, G, TQ, PF) do {                                                 \
    f32x4 s0_ = fz, s1_ = fz;                                                  \
    __builtin_amdgcn_s_setprio(1);                                             \
    s0_ = __builtin_amdgcn_mfma_f32_16x16x32_bf16(P##00, qf[G][0], s0_, 0, 0, 0); \
    s0_ = __builtin_amdgcn_mfma_f32_16x16x32_bf16(P##01, qf[G][1], s0_, 0, 0, 0); \
    s1_ = __builtin_amdgcn_mfma_f32_16x16x32_bf16(P##10, qf[G][0], s1_, 0, 0, 0); \
    s1_ = __builtin_amdgcn_mfma_f32_16x16x32_bf16(P##11, qf[G][1], s1_, 0, 0, 0); \
    __builtin_amdgcn_s_setprio(0);                                             \
    float e_[8];                                                               \
    _Pragma("unroll")                                                          \
    for (int i_ = 0; i_ < 4; ++i_) {                                           \
        float a0_ = ((TQ) >= P##t0[i_]) ? s0_[i_] : -1e9f;                     \
        float a1_ = ((TQ) >= P##t1[i_]) ? s1_[i_] : -1e9f;                     \
        e_[i_]     = __builtin_amdgcn_exp2f(a0_);                              \
        e_[4 + i_] = __builtin_amdgcn_exp2f(a1_);                              \
    }                                                                          \
    union { unsigned int d[4]; bf16x8 v; } pu_;                                \
    pu_.d[0] = __builtin_amdgcn_perm(fbits(e_[1]), fbits(e_[0]), 0x07060302u); \
    pu_.d[1] = __builtin_amdgcn_perm(fbits(e_[3]), fbits(e_[2]), 0x07060302u); \
    pu_.d[2] = __builtin_amdgcn_perm(fbits(e_[5]), fbits(e_[4]), 0x07060302u); \
    pu_.d[3] = __builtin_amdgcn_perm(fbits(e_[7]), fbits(e_[6]), 0x07060302u); \
    PF = pu_.v;                                                                \
    al[G] = __builtin_amdgcn_mfma_f32_16x16x32_bf16(ones, PF, al[G], 0, 0, 0); \
} while (0)

#define DOWIN(P, WI) do {                                                      \
    const int kw_ = kbase + ((WI) << 5);                                       \
    bf16x8 va0_ = *(const bf16x8*)(Vb + kw_);                                  \
    bf16x8 va1_ = *(const bf16x8*)(Vb + 32768 + kw_);                          \
    bf16x8 va2_ = *(const bf16x8*)(Vb + 65536 + kw_);                          \
    bf16x8 va3_ = *(const bf16x8*)(Vb + 98304 + kw_);                          \
    bf16x8 pf0_, pf1_;                                                         \
    DOG(P, 0, tq0, pf0_);                                                      \
    DOG(P, 1, tq1, pf1_);                                                      \
    __builtin_amdgcn_s_setprio(1);                                             \
    ot[0][0] = __builtin_amdgcn_mfma_f32_16x16x32_bf16(va0_, pf0_, ot[0][0], 0, 0, 0); \
    ot[1][0] = __builtin_amdgcn_mfma_f32_16x16x32_bf16(va0_, pf1_, ot[1][0], 0, 0, 0); \
    ot[0][1] = __builtin_amdgcn_mfma_f32_16x16x32_bf16(va1_, pf0_, ot[0][1], 0, 0, 0); \
    ot[1][1] = __builtin_amdgcn_mfma_f32_16x16x32_bf16(va1_, pf1_, ot[1][1], 0, 0, 0); \
    ot[0][2] = __builtin_amdgcn_mfma_f32_16x16x32_bf16(va2_, pf0_, ot[0][2], 0, 0, 0); \
    ot[1][2] = __builtin_amdgcn_mfma_f32_16x16x32_bf16(va2_, pf1_, ot[1][2], 0, 0, 0); \
    ot[0][3] = __builtin_amdgcn_mfma_f32_16x16x32_bf16(va3_, pf0_, ot[0][3], 0, 0, 0); \
    ot[1][3] = __builtin_amdgcn_mfma_f32_16x16x32_bf16(va3_, pf1_, ot[1][3], 0, 0, 0); \
    __builtin_amdgcn_s_setprio(0);                                             \
} while (0)

__global__ __launch_bounds__(256, 3)
void attn_kernel(const unsigned short* __restrict__ qb,
                 const unsigned short* __restrict__ kb,
                 const unsigned short* __restrict__ vt,
                 const int* __restrict__ t_self, const int* __restrict__ t_cross,
                 unsigned short* __restrict__ y)
{
    const int bid = blockIdx.x;
    const int bh = ((bid & 7) << 2) | ((bid >> 3) & 3);   // XCD-local bh group
    const int qt = bid >> 5;                              // 0..63, 32 q each
    const int b = bh >> 3, h = bh & 7;
    const int tid = threadIdx.x, ksplit = tid >> 6, lane = tid & 63;
    const int quad = lane >> 4, r16 = lane & 15;

    const unsigned short* Q = qb + (size_t)bh * 131072;
    const unsigned short* K = kb + (size_t)bh * 131072;
    const unsigned short* V = vt + (size_t)bh * 131072;
    const int* tsb = t_self + b * 1024;
    const int* tcb = t_cross + b * 1024;

    __shared__ unsigned short Op[4][32 * 68];   // bf16 partial O per split
    __shared__ float Ls[4][32];

    const int q0 = qt * 32;

    bf16x8 qf[2][2];
#pragma unroll
    for (int g = 0; g < 2; ++g)
#pragma unroll
        for (int ks = 0; ks < 2; ++ks)
            qf[g][ks] = *(const bf16x8*)(Q + (size_t)(q0 + g * 16 + r16) * 64
                                           + ks * 32 + quad * 8);

    const int* tqp = (qt < 32) ? (tsb + qt * 32) : (tcb + (qt - 32) * 32);
    const int tq0 = tqp[r16];
    const int tq1 = tqp[16 + r16];

    const f32x4 fz = {0.f, 0.f, 0.f, 0.f};
    f32x4 ot[2][4], al[2];
#pragma unroll
    for (int g = 0; g < 2; ++g) {
        al[g] = fz;
#pragma unroll
        for (int nt = 0; nt < 4; ++nt) ot[g][nt] = fz;
    }
    const bf16x8 ones = {(short)0x3F80, (short)0x3F80, (short)0x3F80, (short)0x3F80,
                         (short)0x3F80, (short)0x3F80, (short)0x3F80, (short)0x3F80};

    // this wave's contiguous 512-key range
    const int kbase = ksplit << 9;
    const unsigned short* Kb = K + (size_t)kbase * 64;
    const int* tw = (ksplit < 2) ? (tsb + kbase) : (tcb + (kbase - 1024));
    const unsigned short* Vb = V + (size_t)r16 * 2048 + (quad << 3);

    bf16x8 a00, a01, a10, a11, b00, b01, b10, b11;
    i32x4 at0, at1, bt0, bt1;

    LOADW(a, 0);
    for (int wi = 0; wi < 16; wi += 2) {
        LOADW(b, wi + 1);            // prefetch odd window
        DOWIN(a, wi);
        if (wi < 14) LOADW(a, wi + 2);   // prefetch next even window
        DOWIN(b, wi + 1);
    }

    // write partials (bf16 O per split, fp32 l) and merge
    unsigned short* opw = Op[ksplit];
#pragma unroll
    for (int g = 0; g < 2; ++g)
#pragma unroll
        for (int nt = 0; nt < 4; ++nt) {
            union { unsigned int u[2]; bf16x4 v; } pk;
            pk.u[0] = (unsigned int)f2b(ot[g][nt][0]) | ((unsigned int)f2b(ot[g][nt][1]) << 16);
            pk.u[1] = (unsigned int)f2b(ot[g][nt][2]) | ((unsigned int)f2b(ot[g][nt][3]) << 16);
            *(bf16x4*)(opw + (g * 16 + r16) * 68 + nt * 16 + quad * 4) = pk.v;
        }
    if (quad == 0) {
        Ls[ksplit][r16]      = al[0][0];
        Ls[ksplit][16 + r16] = al[1][0];
    }
    __syncthreads();

    for (int c = tid; c < 512; c += 256) {
        int q = c >> 4, j4 = (c & 15) * 4;
        float l = Ls[0][q] + Ls[1][q] + Ls[2][q] + Ls[3][q];
        float inv = (l > 0.f) ? (1.f / l) : 0.f;
        float s[4] = {0.f, 0.f, 0.f, 0.f};
#pragma unroll
        for (int sp = 0; sp < 4; ++sp) {
            bf16x4 v = *(const bf16x4*)(Op[sp] + q * 68 + j4);
#pragma unroll
            for (int i = 0; i < 4; ++i)
                s[i] += b2f(((const unsigned short*)&v)[i]);
        }
        bf16x4 pk;
#pragma unroll
        for (int i = 0; i < 4; ++i) pk[i] = (short)f2b(s[i] * inv);
        *(bf16x4*)(y + (((size_t)(b * 2048 + q0 + q)) << 9) + h * 64 + j4) = pk;
    }
}

#undef LOADW
#undef DOG
#undef DOWIN

// ---------------------------------------------------------------------------
// proj: Y(8192x512 bf16) @ wtp^T(512x512 bf16) + b -> fp32 out (tuple split).
// Same glds-staged 128x128 GEMM structure as qkv.
// ---------------------------------------------------------------------------
__global__ __launch_bounds__(256)
void proj_kernel(const unsigned short* __restrict__ X,
                 const unsigned short* __restrict__ Wt,
                 const float* __restrict__ bias,
                 float* __restrict__ out)
{
    const int m0 = blockIdx.x * 128, n0 = blockIdx.y * 128;
    __shared__ unsigned short As[128 * 32];
    __shared__ unsigned short Bs[128 * 32];

    const int tid = threadIdx.x, lane = tid & 63, w = tid >> 6;
    const int quad = lane >> 4, r16 = lane & 15;
    const int mrow = (w >> 1) * 64, ncol = (w & 1) * 64;

    const f32x4 fz = {0.f, 0.f, 0.f, 0.f};
    f32x4 acc[4][4];
#pragma unroll
    for (int a = 0; a < 4; ++a)
#pragma unroll
        for (int b = 0; b < 4; ++b) acc[a][b] = fz;

    const int ci   = w << 1;
    const int rofs = lane >> 2, kofs = (lane & 3) * 8;
    const unsigned short* gA = X + (size_t)(m0 + ci * 16 + rofs) * 512 + kofs;
    const unsigned short* gB = Wt + (size_t)(n0 + ci * 16 + rofs) * 512 + kofs;
    unsigned short* lA = As + ci * 512 + lane * 8;
    unsigned short* lB = Bs + ci * 512 + lane * 8;

    for (int k0 = 0; k0 < 512; k0 += 32) {
        glds16(gA + k0, lA);
        glds16(gA + 16 * 512 + k0, lA + 512);
        glds16(gB + k0, lB);
        glds16(gB + 16 * 512 + k0, lB + 512);
        __syncthreads();

        bf16x8 af[4], bfr[4];
#pragma unroll
        for (int ms = 0; ms < 4; ++ms)
            af[ms] = *(const bf16x8*)(As + (mrow + ms * 16 + r16) * 32 + quad * 8);
#pragma unroll
        for (int ns = 0; ns < 4; ++ns)
            bfr[ns] = *(const bf16x8*)(Bs + (ncol + ns * 16 + r16) * 32 + quad * 8);
#pragma unroll
        for (int ms = 0; ms < 4; ++ms)
#pragma unroll
            for (int ns = 0; ns < 4; ++ns)
                acc[ms][ns] = __builtin_amdgcn_mfma_f32_16x16x32_bf16(
                    af[ms], bfr[ns], acc[ms][ns], 0, 0, 0);
        __syncthreads();
    }

#pragma unroll
    for (int ms = 0; ms < 4; ++ms)
#pragma unroll
        for (int ns = 0; ns < 4; ++ns) {
            int n = n0 + ncol + ns * 16 + r16;
            float bb = bias[n];
#pragma unroll
            for (int i = 0; i < 4; ++i) {
                int m = m0 + mrow + ms * 16 + quad * 4 + i;
                int bi = m >> 11, t = m & 2047;
                float v = acc[ms][ns][i] + bb;
                size_t idx = (t < 1024)
                    ? ((size_t)bi * 1024 + t) * 512 + n
                    : (size_t)2097152 + ((size_t)bi * 1024 + (t - 1024)) * 512 + n;
                out[idx] = v;
            }
        }
}

// ---------------------------------------------------------------------------
extern "C" void kernel_launch(void* const* d_in, const int* in_sizes, int n_in,
                              void* d_out, int out_size, void* d_ws, size_t ws_size,
                              hipStream_t stream)
{
    const float* self_seq  = (const float*)d_in[0];
    const float* cross_seq = (const float*)d_in[1];
    const int*   t_self    = (const int*)d_in[2];
    const int*   t_cross   = (const int*)d_in[3];
    const float* W_self    = (const float*)d_in[4];
    const float* b_self    = (const float*)d_in[5];
    const float* W_cross   = (const float*)d_in[6];
    const float* b_cross   = (const float*)d_in[7];
    const float* W_proj    = (const float*)d_in[8];
    const float* b_proj    = (const float*)d_in[9];
    float* out = (float*)d_out;

    // ws (32 MB): q, k, vt, y (4 x 4,194,304 bf16).
    // d_out (33.5 MB fp32) slack holds xb (8 MB) + wt (3 MB) + wtp (0.5 MB)
    // as scratch until proj overwrites everything.
    unsigned short* qbuf = (unsigned short*)d_ws;
    unsigned short* kbuf = qbuf + 4194304;
    unsigned short* vtb  = kbuf + 4194304;
    unsigned short* ybuf = vtb + 4194304;
    unsigned short* xb   = (unsigned short*)d_out;
    unsigned short* wt   = xb + 4194304;
    unsigned short* wtp  = wt + 1572864;

    prep_kernel<<<dim3(2496), 256, 0, stream>>>(
        self_seq, cross_seq, W_self, W_cross, W_proj, xb, wt, wtp);

    qkv_kernel<<<dim3(32, 12, 2), 256, 0, stream>>>(
        xb, wt, b_self, b_cross, qbuf, kbuf, vtb);

    attn_kernel<<<dim3(2048), 256, 0, stream>>>(
        qbuf, kbuf, vtb, t_self, t_cross, ybuf);

    proj_kernel<<<dim3(64, 4), 256, 0, stream>>>(
        ybuf, wtp, b_proj, out);
}

// Round 2
// 177.983 us; speedup vs baseline: 1.4581x; 1.4581x over previous
//
#include <hip/hip_runtime.h>

// ---------------------------------------------------------------------------
// SelfCrossAttention: B=4, T=1024+1024, d=512, H=8, hd=64. fp32 I/O,
// bf16 MFMA internals.
// prep (X->bf16; W_self/W_cross -> wt[n][k], q section pre-scaled by
//       0.125*log2(e) so attention runs in exp2 domain; W_proj -> wtp[n][k])
//   -> qkv (128x128 LDS GEMM staged via global_load_lds width=16, unpadded
//           stride-32 LDS; V stored transposed+window-permuted for K=32 PV)
//   -> attn (GEMM-style LDS pipeline: block = 4 waves x 32q of one bh; all
//            waves sweep all 2048 keys from double-buffered LDS K/V tiles
//            (64 keys/tile) staged via global_load_lds with XOR bank-swizzle
//            (slot ^= row&7, pre-swizzled global source / swizzled ds_read).
//            Key times staged once to LDS. exp2 softmax, l via ones-A MFMA.
//            No key-split -> no merge epilogue; direct normalized write.)
//   -> proj (same glds GEMM, bf16 wtp, fp32 out, tuple split).
// ---------------------------------------------------------------------------

typedef short     bf16x8 __attribute__((ext_vector_type(8)));
typedef short     bf16x4 __attribute__((ext_vector_type(4)));
typedef float     f32x4  __attribute__((ext_vector_type(4)));
typedef int       i32x4  __attribute__((ext_vector_type(4)));

#define DI __device__ __forceinline__

DI unsigned short f2b(float f) {            // fp32 -> bf16 bits, RNE-ish
    union { float f; unsigned int u; } x; x.f = f;
    unsigned int r = x.u + 0x7fffu + ((x.u >> 16) & 1u);
    return (unsigned short)(r >> 16);
}
DI unsigned int fbits(float f) { union { float f; unsigned int u; } x; x.f = f; return x.u; }
DI float bitsf(unsigned int u) { union { unsigned int u; float f; } x; x.u = u; return x.f; }
DI float b2f(unsigned short v) { return bitsf(((unsigned int)v) << 16); }

DI void glds16(const unsigned short* g, unsigned short* l) {   // 16B global->LDS
    __builtin_amdgcn_global_load_lds(
        (const __attribute__((address_space(1))) void*)g,
        (__attribute__((address_space(3))) void*)l, 16, 0, 0);
}
DI void glds16i(const int* g, int* l) {
    __builtin_amdgcn_global_load_lds(
        (const __attribute__((address_space(1))) void*)g,
        (__attribute__((address_space(3))) void*)l, 16, 0, 0);
}

#define QSCALE 0.18033688011112042f   // 0.125 * log2(e): exp2-domain scores

// ---------------------------------------------------------------------------
// prep: [0,2048): X fp32 -> bf16 flat.
//       [2048,2432): W_self/W_cross -> wt[src][n][k], q-section * QSCALE
//       [2432,2496): W_proj -> wtp[n][k]
// ---------------------------------------------------------------------------
__global__ __launch_bounds__(256)
void prep_kernel(const float* __restrict__ Xs, const float* __restrict__ Xc,
                 const float* __restrict__ Ws, const float* __restrict__ Wc,
                 const float* __restrict__ Wp,
                 unsigned short* __restrict__ xb, unsigned short* __restrict__ wt,
                 unsigned short* __restrict__ wtp)
{
    const int bid = blockIdx.x, tid = threadIdx.x;
    if (bid < 2048) {
        int idx = bid * 2048 + tid * 8;
        const float* s = (idx < 2097152) ? (Xs + idx) : (Xc + idx - 2097152);
        f32x4 a0 = *(const f32x4*)s;
        f32x4 a1 = *(const f32x4*)(s + 4);
        bf16x8 v;
#pragma unroll
        for (int j = 0; j < 4; ++j) {
            ((unsigned short*)&v)[j]     = f2b(a0[j]);
            ((unsigned short*)&v)[4 + j] = f2b(a1[j]);
        }
        *(bf16x8*)(xb + idx) = v;
        return;
    }
    __shared__ unsigned short Tt[64 * 72];
    const float* W;
    unsigned short* dst;
    int k0, n0, ldn;
    float sc = 1.0f;
    if (bid < 2432) {
        int tj  = bid - 2048;
        int src = tj >= 192;  tj -= src * 192;
        k0  = (tj / 24) * 64;
        n0  = (tj % 24) * 64;
        W   = src ? Wc : Ws;
        ldn = 1536;
        dst = wt + (size_t)src * 786432;
        if (n0 < 512) sc = QSCALE;
    } else {
        int tj = bid - 2432;
        k0  = (tj >> 3) * 64;
        n0  = (tj & 7) * 64;
        W   = Wp;
        ldn = 512;
        dst = wtp;
    }
#pragma unroll
    for (int r = 0; r < 4; ++r) {
        int g  = tid + r * 256;
        int kr = g >> 4, nc4 = (g & 15) * 4;
        f32x4 v = *(const f32x4*)(W + (size_t)(k0 + kr) * ldn + n0 + nc4);
#pragma unroll
        for (int u = 0; u < 4; ++u)
            Tt[(nc4 + u) * 72 + kr] = f2b(v[u] * sc);
    }
    __syncthreads();
#pragma unroll
    for (int r = 0; r < 2; ++r) {
        int c = tid + r * 256;
        int nl = c >> 3, k8 = (c & 7) * 8;
        *(bf16x8*)(dst + (size_t)(n0 + nl) * 512 + k0 + k8) =
            *(const bf16x8*)(Tt + nl * 72 + k8);
    }
}

// ---------------------------------------------------------------------------
// QKV: xb @ wt^T + bias. 128x128 tile, 256 thr, glds-staged unpadded LDS.
// q/k -> [bh][t][j]; v -> vt[bh][j][t'] with the 32-window key permutation.
// ---------------------------------------------------------------------------
__global__ __launch_bounds__(256)
void qkv_kernel(const unsigned short* __restrict__ xb,
                const unsigned short* __restrict__ wt,
                const float* __restrict__ bs, const float* __restrict__ bc,
                unsigned short* __restrict__ qb, unsigned short* __restrict__ kb,
                unsigned short* __restrict__ vtb)
{
    const int src = blockIdx.z;
    const int m0 = blockIdx.x * 128, n0 = blockIdx.y * 128;
    const float* bias = src ? bc : bs;
    const unsigned short* X = xb + (size_t)src * 2097152;
    const unsigned short* W = wt + (size_t)src * 786432;

    __shared__ unsigned short As[128 * 32];
    __shared__ unsigned short Bs[128 * 32];

    const int tid = threadIdx.x, lane = tid & 63, w = tid >> 6;
    const int quad = lane >> 4, r16 = lane & 15;
    const int mrow = (w >> 1) * 64, ncol = (w & 1) * 64;

    const f32x4 fz = {0.f, 0.f, 0.f, 0.f};
    f32x4 acc[4][4];
#pragma unroll
    for (int a = 0; a < 4; ++a)
#pragma unroll
        for (int b = 0; b < 4; ++b) acc[a][b] = fz;

    // glds staging: chunk ci covers rows [ci*16, ci*16+16); lane -> row/koff
    const int ci   = w << 1;
    const int rofs = lane >> 2, kofs = (lane & 3) * 8;
    const unsigned short* gA = X + (size_t)(m0 + ci * 16 + rofs) * 512 + kofs;
    const unsigned short* gB = W + (size_t)(n0 + ci * 16 + rofs) * 512 + kofs;
    unsigned short* lA = As + ci * 512 + lane * 8;
    unsigned short* lB = Bs + ci * 512 + lane * 8;

    for (int k0 = 0; k0 < 512; k0 += 32) {
        glds16(gA + k0, lA);
        glds16(gA + 16 * 512 + k0, lA + 512);
        glds16(gB + k0, lB);
        glds16(gB + 16 * 512 + k0, lB + 512);
        __syncthreads();

        bf16x8 af[4], bfr[4];
#pragma unroll
        for (int ms = 0; ms < 4; ++ms)
            af[ms] = *(const bf16x8*)(As + (mrow + ms * 16 + r16) * 32 + quad * 8);
#pragma unroll
        for (int ns = 0; ns < 4; ++ns)
            bfr[ns] = *(const bf16x8*)(Bs + (ncol + ns * 16 + r16) * 32 + quad * 8);
#pragma unroll
        for (int ms = 0; ms < 4; ++ms)
#pragma unroll
            for (int ns = 0; ns < 4; ++ns)
                acc[ms][ns] = __builtin_amdgcn_mfma_f32_16x16x32_bf16(
                    af[ms], bfr[ns], acc[ms][ns], 0, 0, 0);
        __syncthreads();
    }

#pragma unroll
    for (int ms = 0; ms < 4; ++ms)
#pragma unroll
        for (int ns = 0; ns < 4; ++ns) {
            int n = n0 + ncol + ns * 16 + r16;
            int sec = n >> 9, col = n & 511;
            int hh = col >> 6, j = col & 63;
            float bb = bias[n] * ((sec == 0) ? QSCALE : 1.0f);
            int mb = m0 + mrow + ms * 16 + quad * 4;
            int bi = mb >> 10, tg0 = (mb & 1023) + (src << 10);
            if (sec == 2) {                 // V: transposed + window-permuted
                bf16x4 pk;
#pragma unroll
                for (int i = 0; i < 4; ++i)
                    pk[i] = (short)f2b(acc[ms][ns][i] + bb);
                int r = tg0 & 31;           // 4-aligned
                int pos = (r < 16) ? (r << 1) : (((r - 16) << 1) + 4);
                int tgp = (tg0 & ~31) + pos;
                *(bf16x4*)(vtb + (((size_t)(bi * 8 + hh) * 64 + j) << 11) + tgp) = pk;
            } else {
                unsigned short* dst = (sec == 0) ? qb : kb;
#pragma unroll
                for (int i = 0; i < 4; ++i)
                    dst[(((size_t)(bi * 8 + hh) * 2048 + tg0 + i) << 6) + j] =
                        f2b(acc[ms][ns][i] + bb);
            }
        }
}

// ---------------------------------------------------------------------------
// attn: S^T flash, exp2 domain, LDS-pipelined. Block 256 thr = 4 waves;
// block = 128 queries (32/wave) of one bh. All waves sweep all 2048 keys
// from double-buffered LDS tiles (64 keys): K 8KB + V 8KB per buffer,
// staged via global_load_lds with XOR swizzle slot^=(row&7) applied on the
// GLOBAL source (LDS dest linear, rule #21) and on the ds_read address.
// Key times staged once (8KB). l via ones-A MFMA; direct write, no merge.
// Grid 512 = 32 bh x 16 qtiles, XCD-swizzled; 2 blocks/CU, LDS 40KB.
// ---------------------------------------------------------------------------

// stage K+V chunks j = w*2, w*2+1 of tile T into buffer BB
#define STAGE(BB, T) do {                                                      \
    _Pragma("unroll")                                                          \
    for (int r_ = 0; r_ < 2; ++r_) {                                           \
        const int j_ = (w << 1) + r_;                                          \
        const int row_ = (j_ << 3) + rofs;                                     \
        glds16(Kg + (size_t)(((T) << 6) + row_) * 64 + lsw,                    \
               &Kl[BB][(j_ << 9) + lane * 8]);                                 \
        glds16(Vg + (size_t)row_ * 2048 + ((T) << 6) + lsw,                    \
               &Vl[BB][(j_ << 9) + lane * 8]);                                 \
    }                                                                          \
} while (0)

#define DOG(G, TQ, PF) do {                                                    \
    f32x4 s0_ = fz, s1_ = fz;                                                  \
    __builtin_amdgcn_s_setprio(1);                                             \
    s0_ = __builtin_amdgcn_mfma_f32_16x16x32_bf16(ka00, qf[G][0], s0_, 0, 0, 0); \
    s0_ = __builtin_amdgcn_mfma_f32_16x16x32_bf16(ka01, qf[G][1], s0_, 0, 0, 0); \
    s1_ = __builtin_amdgcn_mfma_f32_16x16x32_bf16(ka10, qf[G][0], s1_, 0, 0, 0); \
    s1_ = __builtin_amdgcn_mfma_f32_16x16x32_bf16(ka11, qf[G][1], s1_, 0, 0, 0); \
    __builtin_amdgcn_s_setprio(0);                                             \
    float e_[8];                                                               \
    _Pragma("unroll")                                                          \
    for (int i_ = 0; i_ < 4; ++i_) {                                           \
        float a0_ = ((TQ) >= tk0[i_]) ? s0_[i_] : -1e9f;                       \
        float a1_ = ((TQ) >= tk1[i_]) ? s1_[i_] : -1e9f;                       \
        e_[i_]     = __builtin_amdgcn_exp2f(a0_);                              \
        e_[4 + i_] = __builtin_amdgcn_exp2f(a1_);                              \
    }                                                                          \
    union { unsigned int d[4]; bf16x8 v; } pu_;                                \
    pu_.d[0] = __builtin_amdgcn_perm(fbits(e_[1]), fbits(e_[0]), 0x07060302u); \
    pu_.d[1] = __builtin_amdgcn_perm(fbits(e_[3]), fbits(e_[2]), 0x07060302u); \
    pu_.d[2] = __builtin_amdgcn_perm(fbits(e_[5]), fbits(e_[4]), 0x07060302u); \
    pu_.d[3] = __builtin_amdgcn_perm(fbits(e_[7]), fbits(e_[6]), 0x07060302u); \
    PF = pu_.v;                                                                \
    al[G] = __builtin_amdgcn_mfma_f32_16x16x32_bf16(ones, PF, al[G], 0, 0, 0); \
} while (0)

// one 64-key tile T from buffer BB: two 32-key windows
#define DOTILE(BB, T) do {                                                     \
    const unsigned short* Kb_ = Kl[BB];                                        \
    const unsigned short* Vb_ = Vl[BB];                                        \
    _Pragma("unroll")                                                          \
    for (int c_ = 0; c_ < 2; ++c_) {                                           \
        bf16x8 ka00 = *(const bf16x8*)(Kb_ + (c_ * 32 + r16) * 64 + ((quad ^ rsx) << 3));        \
        bf16x8 ka01 = *(const bf16x8*)(Kb_ + (c_ * 32 + r16) * 64 + (((quad + 4) ^ rsx) << 3));  \
        bf16x8 ka10 = *(const bf16x8*)(Kb_ + (c_ * 32 + 16 + r16) * 64 + ((quad ^ rsx) << 3));   \
        bf16x8 ka11 = *(const bf16x8*)(Kb_ + (c_ * 32 + 16 + r16) * 64 + (((quad + 4) ^ rsx) << 3)); \
        i32x4 tk0 = *(const i32x4*)(Ts + ((T) << 6) + c_ * 32 + quad * 4);     \
        i32x4 tk1 = *(const i32x4*)(Ts + ((T) << 6) + c_ * 32 + 16 + quad * 4);\
        const int vs_ = ((4 * c_ + quad) ^ rsx) << 3;                          \
        bf16x8 va0 = *(const bf16x8*)(Vb_ + (r16) * 64 + vs_);                 \
        bf16x8 va1 = *(const bf16x8*)(Vb_ + (16 + r16) * 64 + vs_);            \
        bf16x8 va2 = *(const bf16x8*)(Vb_ + (32 + r16) * 64 + vs_);            \
        bf16x8 va3 = *(const bf16x8*)(Vb_ + (48 + r16) * 64 + vs_);            \
        bf16x8 pf0, pf1;                                                       \
        DOG(0, tq0, pf0);                                                      \
        DOG(1, tq1, pf1);                                                      \
        __builtin_amdgcn_s_setprio(1);                                         \
        ot[0][0] = __builtin_amdgcn_mfma_f32_16x16x32_bf16(va0, pf0, ot[0][0], 0, 0, 0); \
        ot[1][0] = __builtin_amdgcn_mfma_f32_16x16x32_bf16(va0, pf1, ot[1][0], 0, 0, 0); \
        ot[0][1] = __builtin_amdgcn_mfma_f32_16x16x32_bf16(va1, pf0, ot[0][1], 0, 0, 0); \
        ot[1][1] = __builtin_amdgcn_mfma_f32_16x16x32_bf16(va1, pf1, ot[1][1], 0, 0, 0); \
        ot[0][2] = __builtin_amdgcn_mfma_f32_16x16x32_bf16(va2, pf0, ot[0][2], 0, 0, 0); \
        ot[1][2] = __builtin_amdgcn_mfma_f32_16x16x32_bf16(va2, pf1, ot[1][2], 0, 0, 0); \
        ot[0][3] = __builtin_amdgcn_mfma_f32_16x16x32_bf16(va3, pf0, ot[0][3], 0, 0, 0); \
        ot[1][3] = __builtin_amdgcn_mfma_f32_16x16x32_bf16(va3, pf1, ot[1][3], 0, 0, 0); \
        __builtin_amdgcn_s_setprio(0);                                         \
    }                                                                          \
} while (0)

__global__ __launch_bounds__(256, 2)
void attn_kernel(const unsigned short* __restrict__ qb,
                 const unsigned short* __restrict__ kb,
                 const unsigned short* __restrict__ vt,
                 const int* __restrict__ t_self, const int* __restrict__ t_cross,
                 unsigned short* __restrict__ y)
{
    const int bid = blockIdx.x;
    const int bh = ((bid & 7) << 2) | ((bid >> 3) & 3);   // XCD-local bh group
    const int qt = bid >> 5;                              // 0..15, 128 q each
    const int b = bh >> 3, h = bh & 7;
    const int tid = threadIdx.x, w = tid >> 6, lane = tid & 63;
    const int quad = lane >> 4, r16 = lane & 15;
    const int rofs = lane >> 3;                 // staging row-within-chunk
    const int lsw  = ((lane & 7) ^ rofs) << 3;  // pre-swizzled source slot (shorts)
    const int rsx  = r16 & 7;                   // read-side swizzle term

    const unsigned short* Q  = qb + (size_t)bh * 131072;
    const unsigned short* Kg = kb + (size_t)bh * 131072;
    const unsigned short* Vg = vt + (size_t)bh * 131072;
    const int* tsb = t_self + b * 1024;
    const int* tcb = t_cross + b * 1024;

    __shared__ unsigned short Kl[2][4096];   // 8KB per buffer, swizzled
    __shared__ unsigned short Vl[2][4096];   // 8KB per buffer, swizzled
    __shared__ int Ts[2048];                 // all key times (absolute)

    // stage all key times once: 8 x glds16 (2 per wave)
#pragma unroll
    for (int r = 0; r < 2; ++r) {
        const int sg = (w << 1) + r;
        const int* src = (sg < 4) ? (tsb + sg * 256) : (tcb + (sg - 4) * 256);
        glds16i(src + lane * 4, Ts + sg * 256 + lane * 4);
    }

    const int q0w = qt * 128 + w * 32;          // this wave's 32 queries
    bf16x8 qf[2][2];
#pragma unroll
    for (int g = 0; g < 2; ++g)
#pragma unroll
        for (int ks = 0; ks < 2; ++ks)
            qf[g][ks] = *(const bf16x8*)(Q + (size_t)(q0w + g * 16 + r16) * 64
                                           + ks * 32 + quad * 8);
    const int* tqp = (q0w < 1024) ? (tsb + q0w) : (tcb + (q0w - 1024));
    const int tq0 = tqp[r16];
    const int tq1 = tqp[16 + r16];

    const f32x4 fz = {0.f, 0.f, 0.f, 0.f};
    f32x4 ot[2][4], al[2];
#pragma unroll
    for (int g = 0; g < 2; ++g) {
        al[g] = fz;
#pragma unroll
        for (int nt = 0; nt < 4; ++nt) ot[g][nt] = fz;
    }
    const bf16x8 ones = {(short)0x3F80, (short)0x3F80, (short)0x3F80, (short)0x3F80,
                         (short)0x3F80, (short)0x3F80, (short)0x3F80, (short)0x3F80};

    STAGE(0, 0);
    __syncthreads();                            // times + tile 0 ready

    for (int T = 0; T < 32; T += 2) {
        STAGE(1, T + 1);                        // prefetch odd tile
        DOTILE(0, T);
        __syncthreads();                        // odd tile staged; buf0 free
        if (T + 2 < 32) STAGE(0, T + 2);        // prefetch next even tile
        DOTILE(1, T + 1);
        __syncthreads();                        // even tile staged; buf1 free
    }

    // epilogue: normalize and write y directly (no cross-wave merge)
#pragma unroll
    for (int g = 0; g < 2; ++g) {
        const float l = al[g][0];
        const float inv = (l > 0.f) ? (1.f / l) : 0.f;
        const size_t base = (((size_t)(b * 2048 + q0w + g * 16 + r16)) << 9) + h * 64;
#pragma unroll
        for (int nt = 0; nt < 4; ++nt) {
            bf16x4 pk;
#pragma unroll
            for (int i = 0; i < 4; ++i) pk[i] = (short)f2b(ot[g][nt][i] * inv);
            *(bf16x4*)(y + base + nt * 16 + quad * 4) = pk;
        }
    }
}

#undef STAGE
#undef DOG
#undef DOTILE

// ---------------------------------------------------------------------------
// proj: Y(8192x512 bf16) @ wtp^T(512x512 bf16) + b -> fp32 out (tuple split).
// Same glds-staged 128x128 GEMM structure as qkv.
// ---------------------------------------------------------------------------
__global__ __launch_bounds__(256)
void proj_kernel(const unsigned short* __restrict__ X,
                 const unsigned short* __restrict__ Wt,
                 const float* __restrict__ bias,
                 float* __restrict__ out)
{
    const int m0 = blockIdx.x * 128, n0 = blockIdx.y * 128;
    __shared__ unsigned short As[128 * 32];
    __shared__ unsigned short Bs[128 * 32];

    const int tid = threadIdx.x, lane = tid & 63, w = tid >> 6;
    const int quad = lane >> 4, r16 = lane & 15;
    const int mrow = (w >> 1) * 64, ncol = (w & 1) * 64;

    const f32x4 fz = {0.f, 0.f, 0.f, 0.f};
    f32x4 acc[4][4];
#pragma unroll
    for (int a = 0; a < 4; ++a)
#pragma unroll
        for (int b = 0; b < 4; ++b) acc[a][b] = fz;

    const int ci   = w << 1;
    const int rofs = lane >> 2, kofs = (lane & 3) * 8;
    const unsigned short* gA = X + (size_t)(m0 + ci * 16 + rofs) * 512 + kofs;
    const unsigned short* gB = Wt + (size_t)(n0 + ci * 16 + rofs) * 512 + kofs;
    unsigned short* lA = As + ci * 512 + lane * 8;
    unsigned short* lB = Bs + ci * 512 + lane * 8;

    for (int k0 = 0; k0 < 512; k0 += 32) {
        glds16(gA + k0, lA);
        glds16(gA + 16 * 512 + k0, lA + 512);
        glds16(gB + k0, lB);
        glds16(gB + 16 * 512 + k0, lB + 512);
        __syncthreads();

        bf16x8 af[4], bfr[4];
#pragma unroll
        for (int ms = 0; ms < 4; ++ms)
            af[ms] = *(const bf16x8*)(As + (mrow + ms * 16 + r16) * 32 + quad * 8);
#pragma unroll
        for (int ns = 0; ns < 4; ++ns)
            bfr[ns] = *(const bf16x8*)(Bs + (ncol + ns * 16 + r16) * 32 + quad * 8);
#pragma unroll
        for (int ms = 0; ms < 4; ++ms)
#pragma unroll
            for (int ns = 0; ns < 4; ++ns)
                acc[ms][ns] = __builtin_amdgcn_mfma_f32_16x16x32_bf16(
                    af[ms], bfr[ns], acc[ms][ns], 0, 0, 0);
        __syncthreads();
    }

#pragma unroll
    for (int ms = 0; ms < 4; ++ms)
#pragma unroll
        for (int ns = 0; ns < 4; ++ns) {
            int n = n0 + ncol + ns * 16 + r16;
            float bb = bias[n];
#pragma unroll
            for (int i = 0; i < 4; ++i) {
                int m = m0 + mrow + ms * 16 + quad * 4 + i;
                int bi = m >> 11, t = m & 2047;
                float v = acc[ms][ns][i] + bb;
                size_t idx = (t < 1024)
                    ? ((size_t)bi * 1024 + t) * 512 + n
                    : (size_t)2097152 + ((size_t)bi * 1024 + (t - 1024)) * 512 + n;
                out[idx] = v;
            }
        }
}

// ---------------------------------------------------------------------------
extern "C" void kernel_launch(void* const* d_in, const int* in_sizes, int n_in,
                              void* d_out, int out_size, void* d_ws, size_t ws_size,
                              hipStream_t stream)
{
    const float* self_seq  = (const float*)d_in[0];
    const float* cross_seq = (const float*)d_in[1];
    const int*   t_self    = (const int*)d_in[2];
    const int*   t_cross   = (const int*)d_in[3];
    const float* W_self    = (const float*)d_in[4];
    const float* b_self    = (const float*)d_in[5];
    const float* W_cross   = (const float*)d_in[6];
    const float* b_cross   = (const float*)d_in[7];
    const float* W_proj    = (const float*)d_in[8];
    const float* b_proj    = (const float*)d_in[9];
    float* out = (float*)d_out;

    // ws (32 MB): q, k, vt, y (4 x 4,194,304 bf16).
    // d_out (33.5 MB fp32) slack holds xb (8 MB) + wt (3 MB) + wtp (0.5 MB)
    // as scratch until proj overwrites everything.
    unsigned short* qbuf = (unsigned short*)d_ws;
    unsigned short* kbuf = qbuf + 4194304;
    unsigned short* vtb  = kbuf + 4194304;
    unsigned short* ybuf = vtb + 4194304;
    unsigned short* xb   = (unsigned short*)d_out;
    unsigned short* wt   = xb + 4194304;
    unsigned short* wtp  = wt + 1572864;

    prep_kernel<<<dim3(2496), 256, 0, stream>>>(
        self_seq, cross_seq, W_self, W_cross, W_proj, xb, wt, wtp);

    qkv_kernel<<<dim3(32, 12, 2), 256, 0, stream>>>(
        xb, wt, b_self, b_cross, qbuf, kbuf, vtb);

    attn_kernel<<<dim3(512), 256, 0, stream>>>(
        qbuf, kbuf, vtb, t_self, t_cross, ybuf);

    proj_kernel<<<dim3(64, 4), 256, 0, stream>>>(
        ybuf, wtp, b_proj, out);
}

// Round 3
// 175.888 us; speedup vs baseline: 1.4754x; 1.0119x over previous
//
#include <hip/hip_runtime.h>

// ---------------------------------------------------------------------------
// SelfCrossAttention: B=4, T=1024+1024, d=512, H=8, hd=64. fp32 I/O,
// bf16 MFMA internals.
// prep (X->bf16; W_self/W_cross -> wt[n][k], q section pre-scaled by
//       0.125*log2(e) so attention runs in exp2 domain; W_proj -> wtp[n][k])
//   -> qkv (128x128 LDS GEMM staged via global_load_lds width=16, unpadded
//           stride-32 LDS; V stored transposed+window-permuted for K=32 PV)
//   -> attn (GEMM-style LDS pipeline: block = 4 waves x 16q of one bh; all
//            waves sweep all 2048 keys from double-buffered LDS K/V tiles
//            (64 keys/tile) + per-tile key-times, staged via global_load_lds
//            with XOR bank-swizzle on K/V (pre-swizzled global source,
//            swizzled ds_read). 33KB LDS -> 4 blocks/CU, launch_bounds(256,4).
//            exp2 softmax, l via ones-A MFMA; direct normalized write.)
//   -> proj (glds GEMM, 64x128 tile -> 512 blocks = 2/CU).
// ---------------------------------------------------------------------------

typedef short     bf16x8 __attribute__((ext_vector_type(8)));
typedef short     bf16x4 __attribute__((ext_vector_type(4)));
typedef float     f32x4  __attribute__((ext_vector_type(4)));
typedef int       i32x4  __attribute__((ext_vector_type(4)));

#define DI __device__ __forceinline__

DI unsigned short f2b(float f) {            // fp32 -> bf16 bits, RNE-ish
    union { float f; unsigned int u; } x; x.f = f;
    unsigned int r = x.u + 0x7fffu + ((x.u >> 16) & 1u);
    return (unsigned short)(r >> 16);
}
DI unsigned int fbits(float f) { union { float f; unsigned int u; } x; x.f = f; return x.u; }
DI float bitsf(unsigned int u) { union { unsigned int u; float f; } x; x.u = u; return x.f; }
DI float b2f(unsigned short v) { return bitsf(((unsigned int)v) << 16); }

DI void glds16(const unsigned short* g, unsigned short* l) {   // 16B global->LDS
    __builtin_amdgcn_global_load_lds(
        (const __attribute__((address_space(1))) void*)g,
        (__attribute__((address_space(3))) void*)l, 16, 0, 0);
}
DI void glds16i(const int* g, int* l) {
    __builtin_amdgcn_global_load_lds(
        (const __attribute__((address_space(1))) void*)g,
        (__attribute__((address_space(3))) void*)l, 16, 0, 0);
}

#define QSCALE 0.18033688011112042f   // 0.125 * log2(e): exp2-domain scores

// ---------------------------------------------------------------------------
// prep: [0,2048): X fp32 -> bf16 flat.
//       [2048,2432): W_self/W_cross -> wt[src][n][k], q-section * QSCALE
//       [2432,2496): W_proj -> wtp[n][k]
// ---------------------------------------------------------------------------
__global__ __launch_bounds__(256)
void prep_kernel(const float* __restrict__ Xs, const float* __restrict__ Xc,
                 const float* __restrict__ Ws, const float* __restrict__ Wc,
                 const float* __restrict__ Wp,
                 unsigned short* __restrict__ xb, unsigned short* __restrict__ wt,
                 unsigned short* __restrict__ wtp)
{
    const int bid = blockIdx.x, tid = threadIdx.x;
    if (bid < 2048) {
        int idx = bid * 2048 + tid * 8;
        const float* s = (idx < 2097152) ? (Xs + idx) : (Xc + idx - 2097152);
        f32x4 a0 = *(const f32x4*)s;
        f32x4 a1 = *(const f32x4*)(s + 4);
        bf16x8 v;
#pragma unroll
        for (int j = 0; j < 4; ++j) {
            ((unsigned short*)&v)[j]     = f2b(a0[j]);
            ((unsigned short*)&v)[4 + j] = f2b(a1[j]);
        }
        *(bf16x8*)(xb + idx) = v;
        return;
    }
    __shared__ unsigned short Tt[64 * 72];
    const float* W;
    unsigned short* dst;
    int k0, n0, ldn;
    float sc = 1.0f;
    if (bid < 2432) {
        int tj  = bid - 2048;
        int src = tj >= 192;  tj -= src * 192;
        k0  = (tj / 24) * 64;
        n0  = (tj % 24) * 64;
        W   = src ? Wc : Ws;
        ldn = 1536;
        dst = wt + (size_t)src * 786432;
        if (n0 < 512) sc = QSCALE;
    } else {
        int tj = bid - 2432;
        k0  = (tj >> 3) * 64;
        n0  = (tj & 7) * 64;
        W   = Wp;
        ldn = 512;
        dst = wtp;
    }
#pragma unroll
    for (int r = 0; r < 4; ++r) {
        int g  = tid + r * 256;
        int kr = g >> 4, nc4 = (g & 15) * 4;
        f32x4 v = *(const f32x4*)(W + (size_t)(k0 + kr) * ldn + n0 + nc4);
#pragma unroll
        for (int u = 0; u < 4; ++u)
            Tt[(nc4 + u) * 72 + kr] = f2b(v[u] * sc);
    }
    __syncthreads();
#pragma unroll
    for (int r = 0; r < 2; ++r) {
        int c = tid + r * 256;
        int nl = c >> 3, k8 = (c & 7) * 8;
        *(bf16x8*)(dst + (size_t)(n0 + nl) * 512 + k0 + k8) =
            *(const bf16x8*)(Tt + nl * 72 + k8);
    }
}

// ---------------------------------------------------------------------------
// QKV: xb @ wt^T + bias. 128x128 tile, 256 thr, glds-staged unpadded LDS.
// q/k -> [bh][t][j]; v -> vt[bh][j][t'] with the 32-window key permutation.
// ---------------------------------------------------------------------------
__global__ __launch_bounds__(256)
void qkv_kernel(const unsigned short* __restrict__ xb,
                const unsigned short* __restrict__ wt,
                const float* __restrict__ bs, const float* __restrict__ bc,
                unsigned short* __restrict__ qb, unsigned short* __restrict__ kb,
                unsigned short* __restrict__ vtb)
{
    const int src = blockIdx.z;
    const int m0 = blockIdx.x * 128, n0 = blockIdx.y * 128;
    const float* bias = src ? bc : bs;
    const unsigned short* X = xb + (size_t)src * 2097152;
    const unsigned short* W = wt + (size_t)src * 786432;

    __shared__ unsigned short As[128 * 32];
    __shared__ unsigned short Bs[128 * 32];

    const int tid = threadIdx.x, lane = tid & 63, w = tid >> 6;
    const int quad = lane >> 4, r16 = lane & 15;
    const int mrow = (w >> 1) * 64, ncol = (w & 1) * 64;

    const f32x4 fz = {0.f, 0.f, 0.f, 0.f};
    f32x4 acc[4][4];
#pragma unroll
    for (int a = 0; a < 4; ++a)
#pragma unroll
        for (int b = 0; b < 4; ++b) acc[a][b] = fz;

    // glds staging: chunk ci covers rows [ci*16, ci*16+16); lane -> row/koff
    const int ci   = w << 1;
    const int rofs = lane >> 2, kofs = (lane & 3) * 8;
    const unsigned short* gA = X + (size_t)(m0 + ci * 16 + rofs) * 512 + kofs;
    const unsigned short* gB = W + (size_t)(n0 + ci * 16 + rofs) * 512 + kofs;
    unsigned short* lA = As + ci * 512 + lane * 8;
    unsigned short* lB = Bs + ci * 512 + lane * 8;

    for (int k0 = 0; k0 < 512; k0 += 32) {
        glds16(gA + k0, lA);
        glds16(gA + 16 * 512 + k0, lA + 512);
        glds16(gB + k0, lB);
        glds16(gB + 16 * 512 + k0, lB + 512);
        __syncthreads();

        bf16x8 af[4], bfr[4];
#pragma unroll
        for (int ms = 0; ms < 4; ++ms)
            af[ms] = *(const bf16x8*)(As + (mrow + ms * 16 + r16) * 32 + quad * 8);
#pragma unroll
        for (int ns = 0; ns < 4; ++ns)
            bfr[ns] = *(const bf16x8*)(Bs + (ncol + ns * 16 + r16) * 32 + quad * 8);
#pragma unroll
        for (int ms = 0; ms < 4; ++ms)
#pragma unroll
            for (int ns = 0; ns < 4; ++ns)
                acc[ms][ns] = __builtin_amdgcn_mfma_f32_16x16x32_bf16(
                    af[ms], bfr[ns], acc[ms][ns], 0, 0, 0);
        __syncthreads();
    }

#pragma unroll
    for (int ms = 0; ms < 4; ++ms)
#pragma unroll
        for (int ns = 0; ns < 4; ++ns) {
            int n = n0 + ncol + ns * 16 + r16;
            int sec = n >> 9, col = n & 511;
            int hh = col >> 6, j = col & 63;
            float bb = bias[n] * ((sec == 0) ? QSCALE : 1.0f);
            int mb = m0 + mrow + ms * 16 + quad * 4;
            int bi = mb >> 10, tg0 = (mb & 1023) + (src << 10);
            if (sec == 2) {                 // V: transposed + window-permuted
                bf16x4 pk;
#pragma unroll
                for (int i = 0; i < 4; ++i)
                    pk[i] = (short)f2b(acc[ms][ns][i] + bb);
                int r = tg0 & 31;           // 4-aligned
                int pos = (r < 16) ? (r << 1) : (((r - 16) << 1) + 4);
                int tgp = (tg0 & ~31) + pos;
                *(bf16x4*)(vtb + (((size_t)(bi * 8 + hh) * 64 + j) << 11) + tgp) = pk;
            } else {
                unsigned short* dst = (sec == 0) ? qb : kb;
#pragma unroll
                for (int i = 0; i < 4; ++i)
                    dst[(((size_t)(bi * 8 + hh) * 2048 + tg0 + i) << 6) + j] =
                        f2b(acc[ms][ns][i] + bb);
            }
        }
}

// ---------------------------------------------------------------------------
// attn: S^T flash, exp2 domain, LDS-pipelined. Block 256 thr = 4 waves;
// block = 64 queries (16/wave) of one bh. All waves sweep all 2048 keys
// from double-buffered LDS tiles (64 keys): K 8KB + V 8KB per buffer +
// per-tile key-times (256B), staged via global_load_lds. XOR swizzle
// slot^=(row&7) applied on the GLOBAL source (LDS dest linear, rule #21)
// and on the ds_read address. l via ones-A MFMA; direct write, no merge.
// Grid 1024 = 32 bh x 32 qtiles, XCD-swizzled; 4 blocks/CU, LDS 33KB.
// ---------------------------------------------------------------------------

// stage K+V chunks j = w*2, w*2+1 of tile T into buffer BB; wave 3 lanes<16
// stage the tile's 64 key times.
#define STAGE(BB, T) do {                                                      \
    _Pragma("unroll")                                                          \
    for (int r_ = 0; r_ < 2; ++r_) {                                           \
        const int j_ = (w << 1) + r_;                                          \
        const int row_ = (j_ << 3) + rofs;                                     \
        glds16(Kg + (size_t)(((T) << 6) + row_) * 64 + lsw,                    \
               &Kl[BB][(j_ << 9) + lane * 8]);                                 \
        glds16(Vg + (size_t)row_ * 2048 + ((T) << 6) + lsw,                    \
               &Vl[BB][(j_ << 9) + lane * 8]);                                 \
    }                                                                          \
    if (w == 3 && lane < 16) {                                                 \
        const int* tt_ = ((T) < 16) ? (tsb + ((T) << 6)) : (tcb + (((T) - 16) << 6)); \
        glds16i(tt_ + lane * 4, &Tl[BB][lane * 4]);                            \
    }                                                                          \
} while (0)

#define DOG(PF) do {                                                           \
    f32x4 s0_ = fz, s1_ = fz;                                                  \
    __builtin_amdgcn_s_setprio(1);                                             \
    s0_ = __builtin_amdgcn_mfma_f32_16x16x32_bf16(ka00, qf[0], s0_, 0, 0, 0);  \
    s0_ = __builtin_amdgcn_mfma_f32_16x16x32_bf16(ka01, qf[1], s0_, 0, 0, 0);  \
    s1_ = __builtin_amdgcn_mfma_f32_16x16x32_bf16(ka10, qf[0], s1_, 0, 0, 0);  \
    s1_ = __builtin_amdgcn_mfma_f32_16x16x32_bf16(ka11, qf[1], s1_, 0, 0, 0);  \
    __builtin_amdgcn_s_setprio(0);                                             \
    float e_[8];                                                               \
    _Pragma("unroll")                                                          \
    for (int i_ = 0; i_ < 4; ++i_) {                                           \
        float a0_ = (tq0 >= tk0[i_]) ? s0_[i_] : -1e9f;                        \
        float a1_ = (tq0 >= tk1[i_]) ? s1_[i_] : -1e9f;                        \
        e_[i_]     = __builtin_amdgcn_exp2f(a0_);                              \
        e_[4 + i_] = __builtin_amdgcn_exp2f(a1_);                              \
    }                                                                          \
    union { unsigned int d[4]; bf16x8 v; } pu_;                                \
    pu_.d[0] = __builtin_amdgcn_perm(fbits(e_[1]), fbits(e_[0]), 0x07060302u); \
    pu_.d[1] = __builtin_amdgcn_perm(fbits(e_[3]), fbits(e_[2]), 0x07060302u); \
    pu_.d[2] = __builtin_amdgcn_perm(fbits(e_[5]), fbits(e_[4]), 0x07060302u); \
    pu_.d[3] = __builtin_amdgcn_perm(fbits(e_[7]), fbits(e_[6]), 0x07060302u); \
    PF = pu_.v;                                                                \
    al = __builtin_amdgcn_mfma_f32_16x16x32_bf16(ones, PF, al, 0, 0, 0);       \
} while (0)

// one 64-key tile from buffer BB: two 32-key windows
#define DOTILE(BB) do {                                                        \
    const unsigned short* Kb_ = Kl[BB];                                        \
    const unsigned short* Vb_ = Vl[BB];                                        \
    _Pragma("unroll")                                                          \
    for (int c_ = 0; c_ < 2; ++c_) {                                           \
        bf16x8 ka00 = *(const bf16x8*)(Kb_ + (c_ * 32 + r16) * 64 + ((quad ^ rsx) << 3));        \
        bf16x8 ka01 = *(const bf16x8*)(Kb_ + (c_ * 32 + r16) * 64 + (((quad + 4) ^ rsx) << 3));  \
        bf16x8 ka10 = *(const bf16x8*)(Kb_ + (c_ * 32 + 16 + r16) * 64 + ((quad ^ rsx) << 3));   \
        bf16x8 ka11 = *(const bf16x8*)(Kb_ + (c_ * 32 + 16 + r16) * 64 + (((quad + 4) ^ rsx) << 3)); \
        i32x4 tk0 = *(const i32x4*)(Tl[BB] + c_ * 32 + quad * 4);              \
        i32x4 tk1 = *(const i32x4*)(Tl[BB] + c_ * 32 + 16 + quad * 4);         \
        const int vs_ = ((4 * c_ + quad) ^ rsx) << 3;                          \
        bf16x8 va0 = *(const bf16x8*)(Vb_ + (r16) * 64 + vs_);                 \
        bf16x8 va1 = *(const bf16x8*)(Vb_ + (16 + r16) * 64 + vs_);            \
        bf16x8 va2 = *(const bf16x8*)(Vb_ + (32 + r16) * 64 + vs_);            \
        bf16x8 va3 = *(const bf16x8*)(Vb_ + (48 + r16) * 64 + vs_);            \
        bf16x8 pf;                                                             \
        DOG(pf);                                                               \
        __builtin_amdgcn_s_setprio(1);                                         \
        ot[0] = __builtin_amdgcn_mfma_f32_16x16x32_bf16(va0, pf, ot[0], 0, 0, 0); \
        ot[1] = __builtin_amdgcn_mfma_f32_16x16x32_bf16(va1, pf, ot[1], 0, 0, 0); \
        ot[2] = __builtin_amdgcn_mfma_f32_16x16x32_bf16(va2, pf, ot[2], 0, 0, 0); \
        ot[3] = __builtin_amdgcn_mfma_f32_16x16x32_bf16(va3, pf, ot[3], 0, 0, 0); \
        __builtin_amdgcn_s_setprio(0);                                         \
    }                                                                          \
} while (0)

__global__ __launch_bounds__(256, 4)
void attn_kernel(const unsigned short* __restrict__ qb,
                 const unsigned short* __restrict__ kb,
                 const unsigned short* __restrict__ vt,
                 const int* __restrict__ t_self, const int* __restrict__ t_cross,
                 unsigned short* __restrict__ y)
{
    const int bid = blockIdx.x;
    const int bh = ((bid & 7) << 2) | ((bid >> 3) & 3);   // XCD-local bh group
    const int qt = bid >> 5;                              // 0..31, 64 q each
    const int b = bh >> 3, h = bh & 7;
    const int tid = threadIdx.x, w = tid >> 6, lane = tid & 63;
    const int quad = lane >> 4, r16 = lane & 15;
    const int rofs = lane >> 3;                 // staging row-within-chunk
    const int lsw  = ((lane & 7) ^ rofs) << 3;  // pre-swizzled source slot (shorts)
    const int rsx  = r16 & 7;                   // read-side swizzle term

    const unsigned short* Q  = qb + (size_t)bh * 131072;
    const unsigned short* Kg = kb + (size_t)bh * 131072;
    const unsigned short* Vg = vt + (size_t)bh * 131072;
    const int* tsb = t_self + b * 1024;
    const int* tcb = t_cross + b * 1024;

    __shared__ unsigned short Kl[2][4096];   // 8KB per buffer, swizzled
    __shared__ unsigned short Vl[2][4096];   // 8KB per buffer, swizzled
    __shared__ __align__(16) int Tl[2][64];  // per-tile key times

    const int q0w = qt * 64 + w * 16;           // this wave's 16 queries
    bf16x8 qf[2];
#pragma unroll
    for (int ks = 0; ks < 2; ++ks)
        qf[ks] = *(const bf16x8*)(Q + (size_t)(q0w + r16) * 64 + ks * 32 + quad * 8);
    const int* tqp = (q0w < 1024) ? (tsb + q0w) : (tcb + (q0w - 1024));
    const int tq0 = tqp[r16];

    const f32x4 fz = {0.f, 0.f, 0.f, 0.f};
    f32x4 ot[4], al;
    al = fz;
#pragma unroll
    for (int nt = 0; nt < 4; ++nt) ot[nt] = fz;
    const bf16x8 ones = {(short)0x3F80, (short)0x3F80, (short)0x3F80, (short)0x3F80,
                         (short)0x3F80, (short)0x3F80, (short)0x3F80, (short)0x3F80};

    STAGE(0, 0);
    __syncthreads();                            // tile 0 (K/V/times) ready

    for (int T = 0; T < 32; T += 2) {
        STAGE(1, T + 1);                        // prefetch odd tile
        DOTILE(0);
        __syncthreads();                        // odd tile staged; buf0 free
        if (T + 2 < 32) STAGE(0, T + 2);        // prefetch next even tile
        DOTILE(1);
        __syncthreads();                        // even tile staged; buf1 free
    }

    // epilogue: normalize and write y directly (no cross-wave merge)
    {
        const float l = al[0];
        const float inv = (l > 0.f) ? (1.f / l) : 0.f;
        const size_t base = (((size_t)(b * 2048 + q0w + r16)) << 9) + h * 64;
#pragma unroll
        for (int nt = 0; nt < 4; ++nt) {
            bf16x4 pk;
#pragma unroll
            for (int i = 0; i < 4; ++i) pk[i] = (short)f2b(ot[nt][i] * inv);
            *(bf16x4*)(y + base + nt * 16 + quad * 4) = pk;
        }
    }
}

#undef STAGE
#undef DOG
#undef DOTILE

// ---------------------------------------------------------------------------
// proj: Y(8192x512 bf16) @ wtp^T(512x512 bf16) + b -> fp32 out (tuple split).
// glds-staged GEMM, 64x128 tile -> grid 512 = 2 blocks/CU (was 128x128,
// 256 blocks = 1/CU, occupancy-starved).
// ---------------------------------------------------------------------------
__global__ __launch_bounds__(256)
void proj_kernel(const unsigned short* __restrict__ X,
                 const unsigned short* __restrict__ Wt,
                 const float* __restrict__ bias,
                 float* __restrict__ out)
{
    const int m0 = blockIdx.x * 64, n0 = blockIdx.y * 128;
    __shared__ unsigned short As[64 * 32];
    __shared__ unsigned short Bs[128 * 32];

    const int tid = threadIdx.x, lane = tid & 63, w = tid >> 6;
    const int quad = lane >> 4, r16 = lane & 15;
    const int mrow = (w >> 1) * 32, ncol = (w & 1) * 64;

    const f32x4 fz = {0.f, 0.f, 0.f, 0.f};
    f32x4 acc[2][4];
#pragma unroll
    for (int a = 0; a < 2; ++a)
#pragma unroll
        for (int b = 0; b < 4; ++b) acc[a][b] = fz;

    // staging: A chunk w (16 rows), B chunks w*2, w*2+1
    const int rofs = lane >> 2, kofs = (lane & 3) * 8;
    const unsigned short* gA = X + (size_t)(m0 + w * 16 + rofs) * 512 + kofs;
    const unsigned short* gB = Wt + (size_t)(n0 + (w << 1) * 16 + rofs) * 512 + kofs;
    unsigned short* lA = As + w * 512 + lane * 8;
    unsigned short* lB = Bs + (w << 1) * 512 + lane * 8;

    for (int k0 = 0; k0 < 512; k0 += 32) {
        glds16(gA + k0, lA);
        glds16(gB + k0, lB);
        glds16(gB + 16 * 512 + k0, lB + 512);
        __syncthreads();

        bf16x8 af[2], bfr[4];
#pragma unroll
        for (int ms = 0; ms < 2; ++ms)
            af[ms] = *(const bf16x8*)(As + (mrow + ms * 16 + r16) * 32 + quad * 8);
#pragma unroll
        for (int ns = 0; ns < 4; ++ns)
            bfr[ns] = *(const bf16x8*)(Bs + (ncol + ns * 16 + r16) * 32 + quad * 8);
#pragma unroll
        for (int ms = 0; ms < 2; ++ms)
#pragma unroll
            for (int ns = 0; ns < 4; ++ns)
                acc[ms][ns] = __builtin_amdgcn_mfma_f32_16x16x32_bf16(
                    af[ms], bfr[ns], acc[ms][ns], 0, 0, 0);
        __syncthreads();
    }

#pragma unroll
    for (int ms = 0; ms < 2; ++ms)
#pragma unroll
        for (int ns = 0; ns < 4; ++ns) {
            int n = n0 + ncol + ns * 16 + r16;
            float bb = bias[n];
#pragma unroll
            for (int i = 0; i < 4; ++i) {
                int m = m0 + mrow + ms * 16 + quad * 4 + i;
                int bi = m >> 11, t = m & 2047;
                float v = acc[ms][ns][i] + bb;
                size_t idx = (t < 1024)
                    ? ((size_t)bi * 1024 + t) * 512 + n
                    : (size_t)2097152 + ((size_t)bi * 1024 + (t - 1024)) * 512 + n;
                out[idx] = v;
            }
        }
}

// ---------------------------------------------------------------------------
extern "C" void kernel_launch(void* const* d_in, const int* in_sizes, int n_in,
                              void* d_out, int out_size, void* d_ws, size_t ws_size,
                              hipStream_t stream)
{
    const float* self_seq  = (const float*)d_in[0];
    const float* cross_seq = (const float*)d_in[1];
    const int*   t_self    = (const int*)d_in[2];
    const int*   t_cross   = (const int*)d_in[3];
    const float* W_self    = (const float*)d_in[4];
    const float* b_self    = (const float*)d_in[5];
    const float* W_cross   = (const float*)d_in[6];
    const float* b_cross   = (const float*)d_in[7];
    const float* W_proj    = (const float*)d_in[8];
    const float* b_proj    = (const float*)d_in[9];
    float* out = (float*)d_out;

    // ws (32 MB): q, k, vt, y (4 x 4,194,304 bf16).
    // d_out (33.5 MB fp32) slack holds xb (8 MB) + wt (3 MB) + wtp (0.5 MB)
    // as scratch until proj overwrites everything.
    unsigned short* qbuf = (unsigned short*)d_ws;
    unsigned short* kbuf = qbuf + 4194304;
    unsigned short* vtb  = kbuf + 4194304;
    unsigned short* ybuf = vtb + 4194304;
    unsigned short* xb   = (unsigned short*)d_out;
    unsigned short* wt   = xb + 4194304;
    unsigned short* wtp  = wt + 1572864;

    prep_kernel<<<dim3(2496), 256, 0, stream>>>(
        self_seq, cross_seq, W_self, W_cross, W_proj, xb, wt, wtp);

    qkv_kernel<<<dim3(32, 12, 2), 256, 0, stream>>>(
        xb, wt, b_self, b_cross, qbuf, kbuf, vtb);

    attn_kernel<<<dim3(1024), 256, 0, stream>>>(
        qbuf, kbuf, vtb, t_self, t_cross, ybuf);

    proj_kernel<<<dim3(128, 4), 256, 0, stream>>>(
        ybuf, wtp, b_proj, out);
}